// Round 1
// baseline (528.296 us; speedup 1.0000x reference)
//
#include <hip/hip_runtime.h>
#include <hip/hip_bf16.h>
#include <cstdint>
#include <cstddef>

// Problem constants
#define MROWS 8192   // B*L
#define EDIM  1024   // E
#define VDIM  64     // V
#define NTRI  2016   // V*(V-1)/2
#define NTP   2048   // padded NTRI for GEMM tiling

typedef _Float16 half8  __attribute__((ext_vector_type(8)));
typedef _Float16 half4v __attribute__((ext_vector_type(4)));
typedef float    floatx4 __attribute__((ext_vector_type(4)));

typedef __attribute__((address_space(1))) void gvoid;
typedef __attribute__((address_space(3))) void svoid;

__device__ inline void gld_lds16(const _Float16* g, _Float16* l) {
    // async global->LDS, 16B per lane; LDS dest = wave-uniform base + lane*16
    __builtin_amdgcn_global_load_lds((gvoid*)g, (svoid*)l, 16, 0, 0);
}

// ---------------- cast fp32 -> fp16 (with zero padding) ----------------
__global__ __launch_bounds__(256) void cast_f2h(const float* __restrict__ in,
                                                _Float16* __restrict__ out,
                                                int n_valid, int n_total) {
    int idx = (blockIdx.x * 256 + threadIdx.x) * 4;
    if (idx >= n_total) return;
    half4v o;
    if (idx < n_valid) {
        float4 v = *(const float4*)(in + idx);
        o[0] = (_Float16)v.x; o[1] = (_Float16)v.y;
        o[2] = (_Float16)v.z; o[3] = (_Float16)v.w;
    } else {
        o[0] = (_Float16)0.f; o[1] = (_Float16)0.f;
        o[2] = (_Float16)0.f; o[3] = (_Float16)0.f;
    }
    *(half4v*)(out + idx) = o;
}

// ---------------- GEMM: C = act(A @ Bt^T + bias) ----------------
// A: M x K fp16 row-major, Bt: N x K fp16 row-major (i.e. B transposed)
// 128x128 tile per block, 256 threads (4 waves, 2x2 of 64x64), K-chunk 32.
// ACT: 0 = exact gelu, 1 = softplus
template <int ACT>
__global__ __launch_bounds__(256) void gemm_bt(const _Float16* __restrict__ A,
                                               const _Float16* __restrict__ Bt,
                                               const float* __restrict__ bias,
                                               int bias_n,
                                               float* __restrict__ C, int N) {
    __shared__ __align__(16) _Float16 As[128 * 32];
    __shared__ __align__(16) _Float16 Bs[128 * 32];

    const int tid  = threadIdx.x;
    const int n0   = blockIdx.x * 128;   // n-tile fastest: B tile reuse in L2
    const int m0   = blockIdx.y * 128;
    const int w    = tid >> 6;
    const int lane = tid & 63;
    const int wr   = w >> 1;             // wave row (0..1) -> 64 rows
    const int wc   = w & 1;              // wave col (0..1) -> 64 cols
    const int lrow  = lane & 15;         // m (A) / n (B) within 16
    const int lquad = lane >> 4;         // k-group (8 elems each)

    floatx4 acc[4][4] = {};

    // staging: each thread loads 16B (8 halfs); 2 issues per 128x32 tile
    const int r0  = tid >> 2;            // 0..63 tile row
    const int kk0 = (tid & 3) * 8;       // k offset within chunk
    const _Float16* Ag0 = A  + (size_t)(m0 + r0) * EDIM + kk0;
    const _Float16* Ag1 = Ag0 + (size_t)64 * EDIM;
    const _Float16* Bg0 = Bt + (size_t)(n0 + r0) * EDIM + kk0;
    const _Float16* Bg1 = Bg0 + (size_t)64 * EDIM;
    _Float16* As0 = &As[tid * 8];
    _Float16* As1 = As0 + 2048;
    _Float16* Bs0 = &Bs[tid * 8];
    _Float16* Bs1 = Bs0 + 2048;

    const _Float16* ardA = &As[(wr * 64 + lrow) * 32 + lquad * 8];
    const _Float16* brdB = &Bs[(wc * 64 + lrow) * 32 + lquad * 8];

    for (int k0 = 0; k0 < EDIM; k0 += 32) {
        gld_lds16(Ag0 + k0, As0);
        gld_lds16(Ag1 + k0, As1);
        gld_lds16(Bg0 + k0, Bs0);
        gld_lds16(Bg1 + k0, Bs1);
        __syncthreads();  // compiler drains vmcnt before s_barrier

        half8 af[4], bf[4];
#pragma unroll
        for (int t = 0; t < 4; ++t) {
            af[t] = *(const half8*)(ardA + t * 16 * 32);
            bf[t] = *(const half8*)(brdB + t * 16 * 32);
        }
#pragma unroll
        for (int i = 0; i < 4; ++i)
#pragma unroll
            for (int j = 0; j < 4; ++j)
                acc[i][j] = __builtin_amdgcn_mfma_f32_16x16x32_f16(
                    af[i], bf[j], acc[i][j], 0, 0, 0);
        __syncthreads();  // protect LDS before next stage
    }

    // Epilogue. C/D layout (m89-verified): col = lane&15, row = (lane>>4)*4 + reg
    const int cm = m0 + wr * 64 + lquad * 4;
    const int cn = n0 + wc * 64 + lrow;
#pragma unroll
    for (int j = 0; j < 4; ++j) {
        const int gn = cn + j * 16;
        const float bv = (gn < bias_n) ? bias[gn] : 0.0f;
#pragma unroll
        for (int i = 0; i < 4; ++i) {
#pragma unroll
            for (int r = 0; r < 4; ++r) {
                float x = acc[i][j][r] + bv;
                float y;
                if (ACT == 0) {
                    y = 0.5f * x * (1.0f + erff(x * 0.70710678118654752f));
                } else {
                    y = (x > 20.0f) ? x : log1pf(expf(x));
                }
                C[(size_t)(cm + i * 16 + r) * N + gn] = y;
            }
        }
    }
}

// ---------------- LayerNorm (in-place on fp32 H) + fp16 copy ----------------
__global__ __launch_bounds__(256) void ln_kernel(float* __restrict__ H,
                                                 const float* __restrict__ gw,
                                                 const float* __restrict__ bw,
                                                 _Float16* __restrict__ Hh) {
    const int row = blockIdx.x, tid = threadIdx.x;
    float4 v = ((const float4*)(H + (size_t)row * EDIM))[tid];
    float s  = v.x + v.y + v.z + v.w;
    float ss = v.x * v.x + v.y * v.y + v.z * v.z + v.w * v.w;
#pragma unroll
    for (int off = 32; off; off >>= 1) {
        s  += __shfl_down(s, off);
        ss += __shfl_down(ss, off);
    }
    __shared__ float red[8];
    const int w = tid >> 6, lane = tid & 63;
    if (lane == 0) { red[w] = s; red[4 + w] = ss; }
    __syncthreads();
    const float st  = red[0] + red[1] + red[2] + red[3];
    const float sst = red[4] + red[5] + red[6] + red[7];
    const float mu  = st * (1.0f / EDIM);
    const float rs  = 1.0f / sqrtf(sst * (1.0f / EDIM) - mu * mu + 1e-5f);
    float4 gg = ((const float4*)gw)[tid];
    float4 bb = ((const float4*)bw)[tid];
    float4 y;
    y.x = (v.x - mu) * rs * gg.x + bb.x;
    y.y = (v.y - mu) * rs * gg.y + bb.y;
    y.z = (v.z - mu) * rs * gg.z + bb.z;
    y.w = (v.w - mu) * rs * gg.w + bb.w;
    ((float4*)(H + (size_t)row * EDIM))[tid] = y;
    half4v h4;
    h4[0] = (_Float16)y.x; h4[1] = (_Float16)y.y;
    h4[2] = (_Float16)y.z; h4[3] = (_Float16)y.w;
    ((half4v*)(Hh + (size_t)row * EDIM))[tid] = h4;
}

// ---------------- pi = softmax(h @ W_theta^T + b_theta); sp = sqrt(pi) ------
// block = 256 threads, 16 rows per block; lane v = output class, wave w +
// r*4 = row index. fp32 throughout (keeps softmax logits accurate).
__global__ __launch_bounds__(256) void pi_kernel(const float* __restrict__ H,
                                                 const float* __restrict__ Wt,
                                                 const float* __restrict__ bt,
                                                 float* __restrict__ pi_out,
                                                 float* __restrict__ sp) {
    const int v = threadIdx.x & 63;
    const int w = threadIdx.x >> 6;
    const int rbase = blockIdx.x * 16;
    const float4* wr4 = (const float4*)(Wt + (size_t)v * EDIM);
    const float4* h0 = (const float4*)(H + (size_t)(rbase + w) * EDIM);
    const float4* h1 = (const float4*)(H + (size_t)(rbase + w + 4) * EDIM);
    const float4* h2 = (const float4*)(H + (size_t)(rbase + w + 8) * EDIM);
    const float4* h3 = (const float4*)(H + (size_t)(rbase + w + 12) * EDIM);
    float a0 = 0.f, a1 = 0.f, a2 = 0.f, a3 = 0.f;
    for (int k = 0; k < EDIM / 4; ++k) {
        float4 wv = wr4[k];
        float4 x;
        x = h0[k]; a0 += wv.x * x.x + wv.y * x.y + wv.z * x.z + wv.w * x.w;
        x = h1[k]; a1 += wv.x * x.x + wv.y * x.y + wv.z * x.z + wv.w * x.w;
        x = h2[k]; a2 += wv.x * x.x + wv.y * x.y + wv.z * x.z + wv.w * x.w;
        x = h3[k]; a3 += wv.x * x.x + wv.y * x.y + wv.z * x.z + wv.w * x.w;
    }
    const float bv = bt[v];
    float logits[4] = {a0 + bv, a1 + bv, a2 + bv, a3 + bv};
#pragma unroll
    for (int r = 0; r < 4; ++r) {
        float lg = logits[r];
        float m = lg;
#pragma unroll
        for (int off = 32; off; off >>= 1) m = fmaxf(m, __shfl_xor(m, off));
        float e = expf(lg - m);
        float ssum = e;
#pragma unroll
        for (int off = 32; off; off >>= 1) ssum += __shfl_xor(ssum, off);
        float p = e / ssum;
        const int row = rbase + w + r * 4;
        pi_out[(size_t)row * VDIM + v] = p;
        sp[(size_t)row * VDIM + v] = sqrtf(p);
    }
}

// ---------------- Q build: one block per (b,l) row ----------------
// Q[i][j] = Theta[tri(i,j)] * sp[j]/sp[i] (i!=j), Q[i][i] = -rowsum
__global__ __launch_bounds__(256) void q_kernel(const float* __restrict__ Theta,
                                                const float* __restrict__ sp,
                                                float* __restrict__ Q) {
    const int row = blockIdx.x;
    __shared__ float Th[NTRI];
    __shared__ float spv[VDIM];
    const float* trow = Theta + (size_t)row * NTP;
    for (int t = threadIdx.x; t < NTRI; t += 256) Th[t] = trow[t];
    if (threadIdx.x < VDIM) spv[threadIdx.x] = sp[(size_t)row * VDIM + threadIdx.x];
    __syncthreads();

    const int i = threadIdx.x >> 2;   // Q row 0..63
    const int q = threadIdx.x & 3;    // col quarter
    const float rpi = 1.0f / spv[i];
    float vals[16];
    float psum = 0.f;
#pragma unroll
    for (int c = 0; c < 16; ++c) {
        const int j = q * 16 + c;
        float out = 0.f;
        if (j != i) {
            const int a = (i < j) ? i : j;
            const int b = (i < j) ? j : i;
            const int t = a * (127 - a) / 2 + (b - a - 1);
            out = Th[t] * spv[j] * rpi;
            psum += out;
        }
        vals[c] = out;
    }
    // reduce partial rowsums across the 4 threads of this row (consecutive lanes)
    psum += __shfl_xor(psum, 1);
    psum += __shfl_xor(psum, 2);

    float* qrow = Q + ((size_t)row * VDIM + i) * VDIM + q * 16;
    float4* dst = (float4*)qrow;
    dst[0] = make_float4(vals[0], vals[1], vals[2], vals[3]);
    dst[1] = make_float4(vals[4], vals[5], vals[6], vals[7]);
    dst[2] = make_float4(vals[8], vals[9], vals[10], vals[11]);
    dst[3] = make_float4(vals[12], vals[13], vals[14], vals[15]);
    if ((i >> 4) == q) {  // diagonal lies in this thread's chunk
        Q[((size_t)row * VDIM + i) * VDIM + i] = -psum;
    }
}

// ---------------- orchestration ----------------
extern "C" void kernel_launch(void* const* d_in, const int* in_sizes, int n_in,
                              void* d_out, int out_size, void* d_ws, size_t ws_size,
                              hipStream_t stream) {
    const float* hx      = (const float*)d_in[0];
    const float* W_dense = (const float*)d_in[1];
    const float* b_dense = (const float*)d_in[2];
    const float* ln_g    = (const float*)d_in[3];
    const float* ln_b    = (const float*)d_in[4];
    const float* W_theta = (const float*)d_in[5];
    const float* b_theta = (const float*)d_in[6];
    const float* W_Theta = (const float*)d_in[7];
    const float* b_Theta = (const float*)d_in[8];

    uint8_t* ws = (uint8_t*)d_ws;
    // ws layout (120 MB total):
    _Float16* A_h   = (_Float16*)ws;                          // 16 MB (hx fp16; later reused for h fp16)
    _Float16* Wd_h  = (_Float16*)(ws + (size_t)16 * 1048576); //  2 MB
    _Float16* Wt_h  = (_Float16*)(ws + (size_t)18 * 1048576); //  4 MB (2048x1024, zero-padded)
    float*    G     = (float*)(ws + (size_t)22 * 1048576);    // 32 MB (gelu out, then h fp32 in-place)
    float*    Theta = (float*)(ws + (size_t)54 * 1048576);    // 64 MB (8192x2048 padded)
    float*    sp    = (float*)(ws + (size_t)118 * 1048576);   //  2 MB (sqrt(pi))

    float* Q_out  = (float*)d_out;                 // 8192*64*64
    float* pi_out = (float*)d_out + (size_t)MROWS * VDIM * VDIM;

    // 1) casts to fp16 (W_Theta zero-padded to 2048 rows)
    cast_f2h<<<(MROWS * EDIM / 4) / 256, 256, 0, stream>>>(hx, A_h, MROWS * EDIM, MROWS * EDIM);
    cast_f2h<<<(EDIM * EDIM / 4) / 256, 256, 0, stream>>>(W_dense, Wd_h, EDIM * EDIM, EDIM * EDIM);
    cast_f2h<<<(NTP * EDIM / 4) / 256, 256, 0, stream>>>(W_Theta, Wt_h, NTRI * EDIM, NTP * EDIM);

    // 2) dense GEMM + gelu -> G
    gemm_bt<0><<<dim3(EDIM / 128, MROWS / 128), 256, 0, stream>>>(
        A_h, Wd_h, b_dense, EDIM, G, EDIM);

    // 3) LayerNorm in-place; fp16 h into A_h (hx fp16 no longer needed)
    ln_kernel<<<MROWS, 256, 0, stream>>>(G, ln_g, ln_b, A_h);

    // 4) pi + sqrt(pi) (fp32 path)
    pi_kernel<<<MROWS / 16, 256, 0, stream>>>(G, W_theta, b_theta, pi_out, sp);

    // 5) Theta GEMM + softplus -> Theta (padded N=2048, valid bias/cols 2016)
    gemm_bt<1><<<dim3(NTP / 128, MROWS / 128), 256, 0, stream>>>(
        A_h, Wt_h, b_Theta, NTRI, Theta, NTP);

    // 6) Q assembly
    q_kernel<<<MROWS, 256, 0, stream>>>(Theta, sp, Q_out);
}

// Round 2
// 438.267 us; speedup vs baseline: 1.2054x; 1.2054x over previous
//
#include <hip/hip_runtime.h>
#include <hip/hip_bf16.h>
#include <cstdint>
#include <cstddef>

// Problem constants
#define MROWS 8192   // B*L
#define EDIM  1024   // E
#define VDIM  64     // V
#define NTRI  2016   // V*(V-1)/2
#define NTC   2176   // NTRI + 64 (theta logits) padded to 17*128 tiles

typedef _Float16 half8  __attribute__((ext_vector_type(8)));
typedef _Float16 half4v __attribute__((ext_vector_type(4)));
typedef float    floatx4 __attribute__((ext_vector_type(4)));

typedef __attribute__((address_space(1))) void gvoid;
typedef __attribute__((address_space(3))) void svoid;

__device__ inline void gld_lds16(const _Float16* g, _Float16* l) {
    // async global->LDS, 16B per lane; LDS dest = wave-uniform base + lane*16
    __builtin_amdgcn_global_load_lds((gvoid*)g, (svoid*)l, 16, 0, 0);
}

// ---------------- cast fp32 -> fp16 (with zero padding) ----------------
__global__ __launch_bounds__(256) void cast_f2h(const float* __restrict__ in,
                                                _Float16* __restrict__ out,
                                                int n_valid, int n_total) {
    int idx = (blockIdx.x * 256 + threadIdx.x) * 4;
    if (idx >= n_total) return;
    half4v o;
    if (idx < n_valid) {
        float4 v = *(const float4*)(in + idx);
        o[0] = (_Float16)v.x; o[1] = (_Float16)v.y;
        o[2] = (_Float16)v.z; o[3] = (_Float16)v.w;
    } else {
        o[0] = (_Float16)0.f; o[1] = (_Float16)0.f;
        o[2] = (_Float16)0.f; o[3] = (_Float16)0.f;
    }
    *(half4v*)(out + idx) = o;
}

// ---------------- GEMM: C = epilogue(A @ Bt^T) ----------------
// A: M x K fp16 row-major, Bt: N x K fp16 row-major (i.e. B transposed)
// 128x128 tile per block, 256 threads (4 waves, 2x2 of 64x64), K-chunk 32.
// MODE 0: gelu(x + bias[gn])                  (dense layer)
// MODE 1: gn <  NTRI       -> softplus(x + bias[gn])       (Theta)
//         NTRI <= gn < +64 -> x + bias2[gn-NTRI]           (pi logits, raw)
//         else             -> 0                            (padding)
template <int MODE>
__global__ __launch_bounds__(256) void gemm_bt(const _Float16* __restrict__ A,
                                               const _Float16* __restrict__ Bt,
                                               const float* __restrict__ bias,
                                               const float* __restrict__ bias2,
                                               float* __restrict__ C, int N) {
    __shared__ __align__(16) _Float16 As[128 * 32];
    __shared__ __align__(16) _Float16 Bs[128 * 32];

    const int tid  = threadIdx.x;
    const int n0   = blockIdx.x * 128;   // n-tile fastest: B tile reuse in L2
    const int m0   = blockIdx.y * 128;
    const int w    = tid >> 6;
    const int lane = tid & 63;
    const int wr   = w >> 1;             // wave row (0..1) -> 64 rows
    const int wc   = w & 1;              // wave col (0..1) -> 64 cols
    const int lrow  = lane & 15;         // m (A) / n (B) within 16
    const int lquad = lane >> 4;         // k-group (8 elems each)

    floatx4 acc[4][4] = {};

    // staging: each thread loads 16B (8 halfs); 2 issues per 128x32 tile
    const int r0  = tid >> 2;            // 0..63 tile row
    const int kk0 = (tid & 3) * 8;       // k offset within chunk
    const _Float16* Ag0 = A  + (size_t)(m0 + r0) * EDIM + kk0;
    const _Float16* Ag1 = Ag0 + (size_t)64 * EDIM;
    const _Float16* Bg0 = Bt + (size_t)(n0 + r0) * EDIM + kk0;
    const _Float16* Bg1 = Bg0 + (size_t)64 * EDIM;
    _Float16* As0 = &As[tid * 8];
    _Float16* As1 = As0 + 2048;
    _Float16* Bs0 = &Bs[tid * 8];
    _Float16* Bs1 = Bs0 + 2048;

    const _Float16* ardA = &As[(wr * 64 + lrow) * 32 + lquad * 8];
    const _Float16* brdB = &Bs[(wc * 64 + lrow) * 32 + lquad * 8];

    for (int k0 = 0; k0 < EDIM; k0 += 32) {
        gld_lds16(Ag0 + k0, As0);
        gld_lds16(Ag1 + k0, As1);
        gld_lds16(Bg0 + k0, Bs0);
        gld_lds16(Bg1 + k0, Bs1);
        __syncthreads();  // compiler drains vmcnt before s_barrier

        half8 af[4], bf[4];
#pragma unroll
        for (int t = 0; t < 4; ++t) {
            af[t] = *(const half8*)(ardA + t * 16 * 32);
            bf[t] = *(const half8*)(brdB + t * 16 * 32);
        }
#pragma unroll
        for (int i = 0; i < 4; ++i)
#pragma unroll
            for (int j = 0; j < 4; ++j)
                acc[i][j] = __builtin_amdgcn_mfma_f32_16x16x32_f16(
                    af[i], bf[j], acc[i][j], 0, 0, 0);
        __syncthreads();  // protect LDS before next stage
    }

    // Epilogue. C/D layout (m89-verified): col = lane&15, row = (lane>>4)*4 + reg
    const int cm = m0 + wr * 64 + lquad * 4;
    const int cn = n0 + wc * 64 + lrow;
#pragma unroll
    for (int j = 0; j < 4; ++j) {
        const int gn = cn + j * 16;
        float bv;
        if (MODE == 0) {
            bv = bias[gn];
        } else {
            // gn-groups are 16-aligned and NTRI/NTRI+64 are multiples of 16,
            // so these branches are wave-subgroup-uniform.
            if (gn < NTRI)            bv = bias[gn];
            else if (gn < NTRI + VDIM) bv = bias2[gn - NTRI];
            else                      bv = 0.0f;
        }
#pragma unroll
        for (int i = 0; i < 4; ++i) {
#pragma unroll
            for (int r = 0; r < 4; ++r) {
                float x = acc[i][j][r] + bv;
                float y;
                if (MODE == 0) {
                    y = 0.5f * x * (1.0f + erff(x * 0.70710678118654752f));
                } else {
                    if (gn < NTRI) {
                        y = (x > 20.0f) ? x : log1pf(expf(x));
                    } else if (gn < NTRI + VDIM) {
                        y = x;             // raw pi logit
                    } else {
                        y = 0.0f;          // padding
                    }
                }
                C[(size_t)(cm + i * 16 + r) * N + gn] = y;
            }
        }
    }
}

// ---------------- LayerNorm (in-place on fp32 H) + fp16 copy ----------------
__global__ __launch_bounds__(256) void ln_kernel(float* __restrict__ H,
                                                 const float* __restrict__ gw,
                                                 const float* __restrict__ bw,
                                                 _Float16* __restrict__ Hh) {
    const int row = blockIdx.x, tid = threadIdx.x;
    float4 v = ((const float4*)(H + (size_t)row * EDIM))[tid];
    float s  = v.x + v.y + v.z + v.w;
    float ss = v.x * v.x + v.y * v.y + v.z * v.z + v.w * v.w;
#pragma unroll
    for (int off = 32; off; off >>= 1) {
        s  += __shfl_down(s, off);
        ss += __shfl_down(ss, off);
    }
    __shared__ float red[8];
    const int w = tid >> 6, lane = tid & 63;
    if (lane == 0) { red[w] = s; red[4 + w] = ss; }
    __syncthreads();
    const float st  = red[0] + red[1] + red[2] + red[3];
    const float sst = red[4] + red[5] + red[6] + red[7];
    const float mu  = st * (1.0f / EDIM);
    const float rs  = 1.0f / sqrtf(sst * (1.0f / EDIM) - mu * mu + 1e-5f);
    float4 gg = ((const float4*)gw)[tid];
    float4 bb = ((const float4*)bw)[tid];
    float4 y;
    y.x = (v.x - mu) * rs * gg.x + bb.x;
    y.y = (v.y - mu) * rs * gg.y + bb.y;
    y.z = (v.z - mu) * rs * gg.z + bb.z;
    y.w = (v.w - mu) * rs * gg.w + bb.w;
    ((float4*)(H + (size_t)row * EDIM))[tid] = y;
    half4v h4;
    h4[0] = (_Float16)y.x; h4[1] = (_Float16)y.y;
    h4[2] = (_Float16)y.z; h4[3] = (_Float16)y.w;
    ((half4v*)(Hh + (size_t)row * EDIM))[tid] = h4;
}

// ---------------- softmax over the 64 logit columns of Theta buffer --------
// One wave per row; 4 rows per block. Logits live at Theta[row*NTC + NTRI + v].
__global__ __launch_bounds__(256) void softmax_kernel(const float* __restrict__ Theta,
                                                      float* __restrict__ pi_out,
                                                      float* __restrict__ sp) {
    const int lane = threadIdx.x & 63;
    const int row  = blockIdx.x * 4 + (threadIdx.x >> 6);
    float lg = Theta[(size_t)row * NTC + NTRI + lane];
    float m = lg;
#pragma unroll
    for (int off = 32; off; off >>= 1) m = fmaxf(m, __shfl_xor(m, off));
    float e = expf(lg - m);
    float ssum = e;
#pragma unroll
    for (int off = 32; off; off >>= 1) ssum += __shfl_xor(ssum, off);
    float p = e / ssum;
    pi_out[(size_t)row * VDIM + lane] = p;
    sp[(size_t)row * VDIM + lane] = sqrtf(p);
}

// ---------------- Q build: one block per (b,l) row ----------------
// Q[i][j] = Theta[tri(i,j)] * sp[j]/sp[i] (i!=j), Q[i][i] = -rowsum
__global__ __launch_bounds__(256) void q_kernel(const float* __restrict__ Theta,
                                                const float* __restrict__ sp,
                                                float* __restrict__ Q) {
    const int row = blockIdx.x;
    __shared__ float Th[NTRI];
    __shared__ float spv[VDIM];
    const float* trow = Theta + (size_t)row * NTC;
    for (int t = threadIdx.x; t < NTRI; t += 256) Th[t] = trow[t];
    if (threadIdx.x < VDIM) spv[threadIdx.x] = sp[(size_t)row * VDIM + threadIdx.x];
    __syncthreads();

    const int i = threadIdx.x >> 2;   // Q row 0..63
    const int q = threadIdx.x & 3;    // col quarter
    const float rpi = 1.0f / spv[i];
    float vals[16];
    float psum = 0.f;
#pragma unroll
    for (int c = 0; c < 16; ++c) {
        const int j = q * 16 + c;
        float out = 0.f;
        if (j != i) {
            const int a = (i < j) ? i : j;
            const int b = (i < j) ? j : i;
            const int t = a * (127 - a) / 2 + (b - a - 1);
            out = Th[t] * spv[j] * rpi;
            psum += out;
        }
        vals[c] = out;
    }
    // reduce partial rowsums across the 4 threads of this row (consecutive lanes)
    psum += __shfl_xor(psum, 1);
    psum += __shfl_xor(psum, 2);

    float* qrow = Q + ((size_t)row * VDIM + i) * VDIM + q * 16;
    float4* dst = (float4*)qrow;
    dst[0] = make_float4(vals[0], vals[1], vals[2], vals[3]);
    dst[1] = make_float4(vals[4], vals[5], vals[6], vals[7]);
    dst[2] = make_float4(vals[8], vals[9], vals[10], vals[11]);
    dst[3] = make_float4(vals[12], vals[13], vals[14], vals[15]);
    if ((i >> 4) == q) {  // diagonal lies in this thread's chunk
        Q[((size_t)row * VDIM + i) * VDIM + i] = -psum;
    }
}

// ---------------- orchestration ----------------
extern "C" void kernel_launch(void* const* d_in, const int* in_sizes, int n_in,
                              void* d_out, int out_size, void* d_ws, size_t ws_size,
                              hipStream_t stream) {
    const float* hx      = (const float*)d_in[0];
    const float* W_dense = (const float*)d_in[1];
    const float* b_dense = (const float*)d_in[2];
    const float* ln_g    = (const float*)d_in[3];
    const float* ln_b    = (const float*)d_in[4];
    const float* W_theta = (const float*)d_in[5];
    const float* b_theta = (const float*)d_in[6];
    const float* W_Theta = (const float*)d_in[7];
    const float* b_Theta = (const float*)d_in[8];

    uint8_t* ws = (uint8_t*)d_ws;
    // ws layout (~94 MB peak):
    _Float16* A_h  = (_Float16*)ws;                          // 16 MB (hx fp16; later h fp16)
    _Float16* Wd_h = (_Float16*)(ws + (size_t)16 * 1048576); //  2 MB
    _Float16* Wc_h = (_Float16*)(ws + (size_t)18 * 1048576); //  4.25 MB (2176x1024: W_Theta|W_theta|0)
    float*    G    = (float*)(ws + (size_t)23 * 1048576);    // 32 MB (gelu out -> h fp32 in-place)
    float*    Theta= (float*)(ws + (size_t)23 * 1048576);    // 68 MB (8192x2176) — reuses G after LN
    float*    sp   = (float*)(ws + (size_t)92 * 1048576);    //  2 MB (sqrt(pi))

    float* Q_out  = (float*)d_out;                 // 8192*64*64
    float* pi_out = (float*)d_out + (size_t)MROWS * VDIM * VDIM;

    // 1) casts to fp16; combined theta weight = [W_Theta ; W_theta ; zeros]
    cast_f2h<<<(MROWS * EDIM / 4) / 256, 256, 0, stream>>>(hx, A_h, MROWS * EDIM, MROWS * EDIM);
    cast_f2h<<<(EDIM * EDIM / 4) / 256, 256, 0, stream>>>(W_dense, Wd_h, EDIM * EDIM, EDIM * EDIM);
    cast_f2h<<<(NTRI * EDIM / 4) / 256, 256, 0, stream>>>(W_Theta, Wc_h, NTRI * EDIM, NTRI * EDIM);
    cast_f2h<<<((NTC - NTRI) * EDIM / 4) / 256, 256, 0, stream>>>(
        W_theta, Wc_h + (size_t)NTRI * EDIM, VDIM * EDIM, (NTC - NTRI) * EDIM);

    // 2) dense GEMM + gelu -> G
    gemm_bt<0><<<dim3(EDIM / 128, MROWS / 128), 256, 0, stream>>>(
        A_h, Wd_h, b_dense, nullptr, G, EDIM);

    // 3) LayerNorm in-place; fp16 h into A_h (hx fp16 no longer needed)
    ln_kernel<<<MROWS, 256, 0, stream>>>(G, ln_g, ln_b, A_h);

    // 4) combined Theta+logits GEMM (softplus / raw epilogue) -> Theta buffer
    //    (overwrites G, which is dead after ln_kernel)
    gemm_bt<1><<<dim3(NTC / 128, MROWS / 128), 256, 0, stream>>>(
        A_h, Wc_h, b_Theta, b_theta, Theta, NTC);

    // 5) softmax over logit columns -> pi, sqrt(pi)
    softmax_kernel<<<MROWS / 4, 256, 0, stream>>>(Theta, pi_out, sp);

    // 6) Q assembly
    q_kernel<<<MROWS, 256, 0, stream>>>(Theta, sp, Q_out);
}

// Round 3
// 371.151 us; speedup vs baseline: 1.4234x; 1.1808x over previous
//
#include <hip/hip_runtime.h>
#include <hip/hip_bf16.h>
#include <cstdint>
#include <cstddef>

// Problem constants
#define MROWS 8192   // B*L
#define EDIM  1024   // E
#define VDIM  64     // V
#define NTRI  2016   // V*(V-1)/2
#define NTC   2176   // NTRI + 64 (theta logits) padded to 17*128 tiles

typedef _Float16 half8  __attribute__((ext_vector_type(8)));
typedef _Float16 half4v __attribute__((ext_vector_type(4)));
typedef float    floatx4 __attribute__((ext_vector_type(4)));

typedef __attribute__((address_space(1))) void gvoid;
typedef __attribute__((address_space(3))) void svoid;

__device__ inline void gld_lds16(const _Float16* g, _Float16* l) {
    // async global->LDS, 16B per lane; LDS dest = wave-uniform base + lane*16
    __builtin_amdgcn_global_load_lds((gvoid*)g, (svoid*)l, 16, 0, 0);
}

// Fast erf: Abramowitz-Stegun 7.1.26, |err| < 1.5e-7 (hw v_exp_f32)
__device__ inline float fast_erf(float x) {
    float ax = fabsf(x);
    float t = 1.0f / (1.0f + 0.3275911f * ax);
    float p = t * (0.254829592f +
              t * (-0.284496736f +
              t * (1.421413741f +
              t * (-1.453152027f +
              t * 1.061405429f))));
    float r = 1.0f - p * __expf(-ax * ax);
    return copysignf(r, x);
}

// Fast softplus via hw v_exp/v_log; exact identity, stable both tails
__device__ inline float fast_softplus(float x) {
    return fmaxf(x, 0.0f) + __logf(1.0f + __expf(-fabsf(x)));
}

// ---------------- cast fp32 -> fp16 (with zero padding) ----------------
__global__ __launch_bounds__(256) void cast_f2h(const float* __restrict__ in,
                                                _Float16* __restrict__ out,
                                                int n_valid, int n_total) {
    int idx = (blockIdx.x * 256 + threadIdx.x) * 4;
    if (idx >= n_total) return;
    half4v o;
    if (idx < n_valid) {
        float4 v = *(const float4*)(in + idx);
        o[0] = (_Float16)v.x; o[1] = (_Float16)v.y;
        o[2] = (_Float16)v.z; o[3] = (_Float16)v.w;
    } else {
        o[0] = (_Float16)0.f; o[1] = (_Float16)0.f;
        o[2] = (_Float16)0.f; o[3] = (_Float16)0.f;
    }
    *(half4v*)(out + idx) = o;
}

// ---------------- GEMM: C = epilogue(A @ Bt^T) ----------------
// A: M x K fp16 row-major, Bt: N x K fp16 row-major (i.e. B transposed)
// 128x128 tile per block, 256 threads (4 waves, 2x2 of 64x64), K-chunk 32.
// LDS layout is k-chunk XOR-swizzled per row: slot (r, c) holds global
// k-chunk (c ^ s(r)), s(r) = (r>>1)&3. Staging permutes the global source
// (global_load_lds's LDS dest is lane-order-pinned); fragment reads invert.
// This makes each 16-lane ds_read_b128 phase exactly 2-way per bank (free).
// MODE 0: gelu(x + bias[gn])                  (dense layer)
// MODE 1: gn <  NTRI       -> softplus(x + bias[gn])       (Theta)
//         NTRI <= gn < +64 -> x + bias2[gn-NTRI]           (pi logits, raw)
//         else             -> 0                            (padding)
template <int MODE>
__global__ __launch_bounds__(256) void gemm_bt(const _Float16* __restrict__ A,
                                               const _Float16* __restrict__ Bt,
                                               const float* __restrict__ bias,
                                               const float* __restrict__ bias2,
                                               float* __restrict__ C, int N) {
    __shared__ __align__(16) _Float16 As[128 * 32];
    __shared__ __align__(16) _Float16 Bs[128 * 32];

    const int tid  = threadIdx.x;
    const int n0   = blockIdx.x * 128;   // n-tile fastest: B tile reuse in L2
    const int m0   = blockIdx.y * 128;
    const int w    = tid >> 6;
    const int lane = tid & 63;
    const int wr   = w >> 1;             // wave row (0..1) -> 64 rows
    const int wc   = w & 1;              // wave col (0..1) -> 64 cols
    const int lrow  = lane & 15;         // m (A) / n (B) within 16
    const int lquad = lane >> 4;         // k-group (8 elems each)

    floatx4 acc[4][4] = {};

    // staging: each thread loads 16B (8 halfs); 2 issues per 128x32 tile
    const int r0  = tid >> 2;            // 0..63 tile row
    const int sw0 = (r0 >> 1) & 3;       // XOR swizzle for this row
    const int kk0 = ((tid & 3) ^ sw0) * 8;  // permuted global k offset
    const _Float16* Ag0 = A  + (size_t)(m0 + r0) * EDIM + kk0;
    const _Float16* Ag1 = Ag0 + (size_t)64 * EDIM;   // row+64: same swizzle (r mod 8 equal)
    const _Float16* Bg0 = Bt + (size_t)(n0 + r0) * EDIM + kk0;
    const _Float16* Bg1 = Bg0 + (size_t)64 * EDIM;
    _Float16* As0 = &As[tid * 8];
    _Float16* As1 = As0 + 2048;
    _Float16* Bs0 = &Bs[tid * 8];
    _Float16* Bs1 = Bs0 + 2048;

    // fragment read: row = wr*64 + t*16 + lrow (row mod 8 == lrow mod 8),
    // chunk slot = lquad ^ s(row)
    const int swr = (lrow >> 1) & 3;
    const _Float16* ardA = &As[(wr * 64 + lrow) * 32 + ((lquad ^ swr) * 8)];
    const _Float16* brdB = &Bs[(wc * 64 + lrow) * 32 + ((lquad ^ swr) * 8)];

    for (int k0 = 0; k0 < EDIM; k0 += 32) {
        gld_lds16(Ag0 + k0, As0);
        gld_lds16(Ag1 + k0, As1);
        gld_lds16(Bg0 + k0, Bs0);
        gld_lds16(Bg1 + k0, Bs1);
        __syncthreads();  // compiler drains vmcnt before s_barrier

        half8 af[4], bf[4];
#pragma unroll
        for (int t = 0; t < 4; ++t) {
            af[t] = *(const half8*)(ardA + t * 16 * 32);
            bf[t] = *(const half8*)(brdB + t * 16 * 32);
        }
#pragma unroll
        for (int i = 0; i < 4; ++i)
#pragma unroll
            for (int j = 0; j < 4; ++j)
                acc[i][j] = __builtin_amdgcn_mfma_f32_16x16x32_f16(
                    af[i], bf[j], acc[i][j], 0, 0, 0);
        __syncthreads();  // protect LDS before next stage
    }

    // Epilogue. C/D layout (m89-verified): col = lane&15, row = (lane>>4)*4 + reg
    const int cm = m0 + wr * 64 + lquad * 4;
    const int cn = n0 + wc * 64 + lrow;
#pragma unroll
    for (int j = 0; j < 4; ++j) {
        const int gn = cn + j * 16;
        float bv;
        if (MODE == 0) {
            bv = bias[gn];
        } else {
            // gn-groups are 16-aligned and NTRI/NTRI+64 are multiples of 16,
            // so these branches are wave-subgroup-uniform.
            if (gn < NTRI)            bv = bias[gn];
            else if (gn < NTRI + VDIM) bv = bias2[gn - NTRI];
            else                      bv = 0.0f;
        }
#pragma unroll
        for (int i = 0; i < 4; ++i) {
#pragma unroll
            for (int r = 0; r < 4; ++r) {
                float x = acc[i][j][r] + bv;
                float y;
                if (MODE == 0) {
                    y = 0.5f * x * (1.0f + fast_erf(x * 0.70710678118654752f));
                } else {
                    if (gn < NTRI) {
                        y = fast_softplus(x);
                    } else if (gn < NTRI + VDIM) {
                        y = x;             // raw pi logit
                    } else {
                        y = 0.0f;          // padding
                    }
                }
                C[(size_t)(cm + i * 16 + r) * N + gn] = y;
            }
        }
    }
}

// ---------------- LayerNorm (in-place on fp32 H) + fp16 copy ----------------
__global__ __launch_bounds__(256) void ln_kernel(float* __restrict__ H,
                                                 const float* __restrict__ gw,
                                                 const float* __restrict__ bw,
                                                 _Float16* __restrict__ Hh) {
    const int row = blockIdx.x, tid = threadIdx.x;
    float4 v = ((const float4*)(H + (size_t)row * EDIM))[tid];
    float s  = v.x + v.y + v.z + v.w;
    float ss = v.x * v.x + v.y * v.y + v.z * v.z + v.w * v.w;
#pragma unroll
    for (int off = 32; off; off >>= 1) {
        s  += __shfl_down(s, off);
        ss += __shfl_down(ss, off);
    }
    __shared__ float red[8];
    const int w = tid >> 6, lane = tid & 63;
    if (lane == 0) { red[w] = s; red[4 + w] = ss; }
    __syncthreads();
    const float st  = red[0] + red[1] + red[2] + red[3];
    const float sst = red[4] + red[5] + red[6] + red[7];
    const float mu  = st * (1.0f / EDIM);
    const float rs  = 1.0f / sqrtf(sst * (1.0f / EDIM) - mu * mu + 1e-5f);
    float4 gg = ((const float4*)gw)[tid];
    float4 bb = ((const float4*)bw)[tid];
    float4 y;
    y.x = (v.x - mu) * rs * gg.x + bb.x;
    y.y = (v.y - mu) * rs * gg.y + bb.y;
    y.z = (v.z - mu) * rs * gg.z + bb.z;
    y.w = (v.w - mu) * rs * gg.w + bb.w;
    ((float4*)(H + (size_t)row * EDIM))[tid] = y;
    half4v h4;
    h4[0] = (_Float16)y.x; h4[1] = (_Float16)y.y;
    h4[2] = (_Float16)y.z; h4[3] = (_Float16)y.w;
    ((half4v*)(Hh + (size_t)row * EDIM))[tid] = h4;
}

// ---------------- softmax over the 64 logit columns of Theta buffer --------
// One wave per row; 4 rows per block. Logits live at Theta[row*NTC + NTRI + v].
__global__ __launch_bounds__(256) void softmax_kernel(const float* __restrict__ Theta,
                                                      float* __restrict__ pi_out,
                                                      float* __restrict__ sp) {
    const int lane = threadIdx.x & 63;
    const int row  = blockIdx.x * 4 + (threadIdx.x >> 6);
    float lg = Theta[(size_t)row * NTC + NTRI + lane];
    float m = lg;
#pragma unroll
    for (int off = 32; off; off >>= 1) m = fmaxf(m, __shfl_xor(m, off));
    float e = __expf(lg - m);
    float ssum = e;
#pragma unroll
    for (int off = 32; off; off >>= 1) ssum += __shfl_xor(ssum, off);
    float p = e / ssum;
    pi_out[(size_t)row * VDIM + lane] = p;
    sp[(size_t)row * VDIM + lane] = sqrtf(p);
}

// ---------------- Q build: one block per (b,l) row ----------------
// Q[i][j] = Theta[tri(i,j)] * sp[j]/sp[i] (i!=j), Q[i][i] = -rowsum
__global__ __launch_bounds__(256) void q_kernel(const float* __restrict__ Theta,
                                                const float* __restrict__ sp,
                                                float* __restrict__ Q) {
    const int row = blockIdx.x;
    __shared__ float Th[NTRI];
    __shared__ float spv[VDIM];
    const float* trow = Theta + (size_t)row * NTC;
    for (int t = threadIdx.x; t < NTRI; t += 256) Th[t] = trow[t];
    if (threadIdx.x < VDIM) spv[threadIdx.x] = sp[(size_t)row * VDIM + threadIdx.x];
    __syncthreads();

    const int i = threadIdx.x >> 2;   // Q row 0..63
    const int q = threadIdx.x & 3;    // col quarter
    const float rpi = 1.0f / spv[i];
    float vals[16];
    float psum = 0.f;
#pragma unroll
    for (int c = 0; c < 16; ++c) {
        const int j = q * 16 + c;
        float out = 0.f;
        if (j != i) {
            const int a = (i < j) ? i : j;
            const int b = (i < j) ? j : i;
            const int t = a * (127 - a) / 2 + (b - a - 1);
            out = Th[t] * spv[j] * rpi;
            psum += out;
        }
        vals[c] = out;
    }
    // reduce partial rowsums across the 4 threads of this row (consecutive lanes)
    psum += __shfl_xor(psum, 1);
    psum += __shfl_xor(psum, 2);

    float* qrow = Q + ((size_t)row * VDIM + i) * VDIM + q * 16;
    float4* dst = (float4*)qrow;
    dst[0] = make_float4(vals[0], vals[1], vals[2], vals[3]);
    dst[1] = make_float4(vals[4], vals[5], vals[6], vals[7]);
    dst[2] = make_float4(vals[8], vals[9], vals[10], vals[11]);
    dst[3] = make_float4(vals[12], vals[13], vals[14], vals[15]);
    if ((i >> 4) == q) {  // diagonal lies in this thread's chunk
        Q[((size_t)row * VDIM + i) * VDIM + i] = -psum;
    }
}

// ---------------- orchestration ----------------
extern "C" void kernel_launch(void* const* d_in, const int* in_sizes, int n_in,
                              void* d_out, int out_size, void* d_ws, size_t ws_size,
                              hipStream_t stream) {
    const float* hx      = (const float*)d_in[0];
    const float* W_dense = (const float*)d_in[1];
    const float* b_dense = (const float*)d_in[2];
    const float* ln_g    = (const float*)d_in[3];
    const float* ln_b    = (const float*)d_in[4];
    const float* W_theta = (const float*)d_in[5];
    const float* b_theta = (const float*)d_in[6];
    const float* W_Theta = (const float*)d_in[7];
    const float* b_Theta = (const float*)d_in[8];

    uint8_t* ws = (uint8_t*)d_ws;
    // ws layout (~94 MB peak):
    _Float16* A_h  = (_Float16*)ws;                          // 16 MB (hx fp16; later h fp16)
    _Float16* Wd_h = (_Float16*)(ws + (size_t)16 * 1048576); //  2 MB
    _Float16* Wc_h = (_Float16*)(ws + (size_t)18 * 1048576); //  4.25 MB (2176x1024: W_Theta|W_theta|0)
    float*    G    = (float*)(ws + (size_t)23 * 1048576);    // 32 MB (gelu out -> h fp32 in-place)
    float*    Theta= (float*)(ws + (size_t)23 * 1048576);    // 68 MB (8192x2176) — reuses G after LN
    float*    sp   = (float*)(ws + (size_t)92 * 1048576);    //  2 MB (sqrt(pi))

    float* Q_out  = (float*)d_out;                 // 8192*64*64
    float* pi_out = (float*)d_out + (size_t)MROWS * VDIM * VDIM;

    // 1) casts to fp16; combined theta weight = [W_Theta ; W_theta ; zeros]
    cast_f2h<<<(MROWS * EDIM / 4) / 256, 256, 0, stream>>>(hx, A_h, MROWS * EDIM, MROWS * EDIM);
    cast_f2h<<<(EDIM * EDIM / 4) / 256, 256, 0, stream>>>(W_dense, Wd_h, EDIM * EDIM, EDIM * EDIM);
    cast_f2h<<<(NTRI * EDIM / 4) / 256, 256, 0, stream>>>(W_Theta, Wc_h, NTRI * EDIM, NTRI * EDIM);
    cast_f2h<<<((NTC - NTRI) * EDIM / 4) / 256, 256, 0, stream>>>(
        W_theta, Wc_h + (size_t)NTRI * EDIM, VDIM * EDIM, (NTC - NTRI) * EDIM);

    // 2) dense GEMM + gelu -> G
    gemm_bt<0><<<dim3(EDIM / 128, MROWS / 128), 256, 0, stream>>>(
        A_h, Wd_h, b_dense, nullptr, G, EDIM);

    // 3) LayerNorm in-place; fp16 h into A_h (hx fp16 no longer needed)
    ln_kernel<<<MROWS, 256, 0, stream>>>(G, ln_g, ln_b, A_h);

    // 4) combined Theta+logits GEMM (softplus / raw epilogue) -> Theta buffer
    //    (overwrites G, which is dead after ln_kernel)
    gemm_bt<1><<<dim3(NTC / 128, MROWS / 128), 256, 0, stream>>>(
        A_h, Wc_h, b_Theta, b_theta, Theta, NTC);

    // 5) softmax over logit columns -> pi, sqrt(pi)
    softmax_kernel<<<MROWS / 4, 256, 0, stream>>>(Theta, pi_out, sp);

    // 6) Q assembly
    q_kernel<<<MROWS, 256, 0, stream>>>(Theta, sp, Q_out);
}

// Round 4
// 352.195 us; speedup vs baseline: 1.5000x; 1.0538x over previous
//
#include <hip/hip_runtime.h>
#include <hip/hip_bf16.h>
#include <cstdint>
#include <cstddef>

// Problem constants
#define MROWS 8192   // B*L
#define EDIM  1024   // E
#define VDIM  64     // V
#define NTRI  2016   // V*(V-1)/2
#define NTC   2176   // NTRI + 64 (theta logits) padded to 17*128 tiles

typedef _Float16 half8  __attribute__((ext_vector_type(8)));
typedef _Float16 half4v __attribute__((ext_vector_type(4)));
typedef float    floatx4 __attribute__((ext_vector_type(4)));

typedef __attribute__((address_space(1))) void gvoid;
typedef __attribute__((address_space(3))) void svoid;

__device__ inline void gld_lds16(const _Float16* g, _Float16* l) {
    // async global->LDS, 16B per lane; LDS dest = wave-uniform base + lane*16
    __builtin_amdgcn_global_load_lds((gvoid*)g, (svoid*)l, 16, 0, 0);
}

// Fast erf: Abramowitz-Stegun 7.1.26, |err| < 1.5e-7 (hw v_exp_f32)
__device__ inline float fast_erf(float x) {
    float ax = fabsf(x);
    float t = 1.0f / (1.0f + 0.3275911f * ax);
    float p = t * (0.254829592f +
              t * (-0.284496736f +
              t * (1.421413741f +
              t * (-1.453152027f +
              t * 1.061405429f))));
    float r = 1.0f - p * __expf(-ax * ax);
    return copysignf(r, x);
}

// Fast softplus via hw v_exp/v_log; exact identity, stable both tails
__device__ inline float fast_softplus(float x) {
    return fmaxf(x, 0.0f) + __logf(1.0f + __expf(-fabsf(x)));
}

// ---------------- cast fp32 -> fp16 (with zero padding) ----------------
__global__ __launch_bounds__(256) void cast_f2h(const float* __restrict__ in,
                                                _Float16* __restrict__ out,
                                                int n_valid, int n_total) {
    int idx = (blockIdx.x * 256 + threadIdx.x) * 4;
    if (idx >= n_total) return;
    half4v o;
    if (idx < n_valid) {
        float4 v = *(const float4*)(in + idx);
        o[0] = (_Float16)v.x; o[1] = (_Float16)v.y;
        o[2] = (_Float16)v.z; o[3] = (_Float16)v.w;
    } else {
        o[0] = (_Float16)0.f; o[1] = (_Float16)0.f;
        o[2] = (_Float16)0.f; o[3] = (_Float16)0.f;
    }
    *(half4v*)(out + idx) = o;
}

// ---------------- GEMM: C = epilogue(A @ Bt^T) ----------------
// A: M x K fp16 row-major, Bt: N x K fp16 row-major (i.e. B transposed)
// 128x128 tile per block, 256 threads (4 waves, 2x2 of 64x64), K-chunk 64.
//
// XCD-aware grid: 1D launch; block b -> xcd = b&7 (HW round-robin), and
// m-tile = xcd + 8*(slot/ntiles_n). All n-blocks of one m-tile run on the
// same XCD -> A-tile fetched from HBM once, then L2-hit (latency 900->~200).
//
// LDS: rows of 64 halfs (128 B). Slot (r, c) (c = 16B chunk 0..7) holds
// global chunk (c ^ (r&7)); staging permutes the global source within each
// row's 128 B line (global_load_lds LDS dest is lane-order-pinned);
// fragment reads invert -> every 16-lane ds_read_b128 phase is 2-way (free).
//
// MODE 0: gelu(x + bias[gn])                  (dense layer)
// MODE 1: gn <  NTRI       -> softplus(x + bias[gn])       (Theta)
//         NTRI <= gn < +64 -> x + bias2[gn-NTRI]           (pi logits, raw)
//         else             -> 0                            (padding)
template <int MODE>
__global__ __launch_bounds__(256) void gemm_bt(const _Float16* __restrict__ A,
                                               const _Float16* __restrict__ Bt,
                                               const float* __restrict__ bias,
                                               const float* __restrict__ bias2,
                                               float* __restrict__ C, int N) {
    __shared__ __align__(16) _Float16 As[128 * 64];
    __shared__ __align__(16) _Float16 Bs[128 * 64];

    const int tid  = threadIdx.x;
    // XCD-aware tile mapping
    const int ng   = N >> 7;             // n-tiles (17 or 8)
    const int xcd  = blockIdx.x & 7;
    const int slot = blockIdx.x >> 3;
    const int mg   = slot / ng;
    const int nn   = slot - mg * ng;
    const int m0   = (xcd + mg * 8) * 128;
    const int n0   = nn * 128;

    const int w    = tid >> 6;
    const int lane = tid & 63;
    const int wr   = w >> 1;             // wave row (0..1) -> 64 rows
    const int wc   = w & 1;              // wave col (0..1) -> 64 cols
    const int lrow  = lane & 15;         // m (A) / n (B) within 16
    const int lquad = lane >> 4;         // k-group (8 elems each)

    floatx4 acc[4][4] = {};

    // staging: thread t -> tile row r0 = t>>3 (+32 per call), chunk c0 = t&7.
    // LDS dest (pinned) = slot (r0, c0); global source chunk g = c0 ^ (r0&7).
    const int r0 = tid >> 3;             // 0..31
    const int c0 = tid & 7;
    const int g  = (c0 ^ (r0 & 7)) * 8;  // halfs offset within row's 64
    const _Float16* Ag[4];
    const _Float16* Bg[4];
#pragma unroll
    for (int call = 0; call < 4; ++call) {
        Ag[call] = A  + (size_t)(m0 + call * 32 + r0) * EDIM + g;
        Bg[call] = Bt + (size_t)(n0 + call * 32 + r0) * EDIM + g;
    }
    _Float16* AsD = &As[tid * 8];        // call c adds c*2048 halfs
    _Float16* BsD = &Bs[tid * 8];

    // fragment read bases: row = wr*64 + i*16 + lrow (64 halfs per row)
    const int swr = lrow & 7;
    const _Float16* ardA = &As[(wr * 64 + lrow) * 64];
    const _Float16* brdB = &Bs[(wc * 64 + lrow) * 64];

    for (int k0 = 0; k0 < EDIM; k0 += 64) {
#pragma unroll
        for (int call = 0; call < 4; ++call) {
            gld_lds16(Ag[call] + k0, AsD + call * 2048);
            gld_lds16(Bg[call] + k0, BsD + call * 2048);
        }
        __syncthreads();  // drains vmcnt before s_barrier

#pragma unroll
        for (int kstep = 0; kstep < 2; ++kstep) {
            const int soff = ((kstep * 4 + lquad) ^ swr) * 8;
            half8 af[4], bf[4];
#pragma unroll
            for (int t = 0; t < 4; ++t) {
                af[t] = *(const half8*)(ardA + t * 16 * 64 + soff);
                bf[t] = *(const half8*)(brdB + t * 16 * 64 + soff);
            }
#pragma unroll
            for (int i = 0; i < 4; ++i)
#pragma unroll
                for (int j = 0; j < 4; ++j)
                    acc[i][j] = __builtin_amdgcn_mfma_f32_16x16x32_f16(
                        af[i], bf[j], acc[i][j], 0, 0, 0);
        }
        __syncthreads();  // protect LDS before next stage
    }

    // Epilogue. C/D layout (m89-verified): col = lane&15, row = (lane>>4)*4 + reg
    const int cm = m0 + wr * 64 + lquad * 4;
    const int cn = n0 + wc * 64 + lrow;
#pragma unroll
    for (int j = 0; j < 4; ++j) {
        const int gn = cn + j * 16;
        float bv;
        if (MODE == 0) {
            bv = bias[gn];
        } else {
            // gn-groups are 16-aligned and NTRI/NTRI+64 are multiples of 16,
            // so these branches are wave-subgroup-uniform.
            if (gn < NTRI)             bv = bias[gn];
            else if (gn < NTRI + VDIM) bv = bias2[gn - NTRI];
            else                       bv = 0.0f;
        }
#pragma unroll
        for (int i = 0; i < 4; ++i) {
#pragma unroll
            for (int r = 0; r < 4; ++r) {
                float x = acc[i][j][r] + bv;
                float y;
                if (MODE == 0) {
                    y = 0.5f * x * (1.0f + fast_erf(x * 0.70710678118654752f));
                } else {
                    if (gn < NTRI) {
                        y = fast_softplus(x);
                    } else if (gn < NTRI + VDIM) {
                        y = x;             // raw pi logit
                    } else {
                        y = 0.0f;          // padding
                    }
                }
                C[(size_t)(cm + i * 16 + r) * N + gn] = y;
            }
        }
    }
}

// ---------------- LayerNorm (in-place on fp32 H) + fp16 copy ----------------
__global__ __launch_bounds__(256) void ln_kernel(float* __restrict__ H,
                                                 const float* __restrict__ gw,
                                                 const float* __restrict__ bw,
                                                 _Float16* __restrict__ Hh) {
    const int row = blockIdx.x, tid = threadIdx.x;
    float4 v = ((const float4*)(H + (size_t)row * EDIM))[tid];
    float s  = v.x + v.y + v.z + v.w;
    float ss = v.x * v.x + v.y * v.y + v.z * v.z + v.w * v.w;
#pragma unroll
    for (int off = 32; off; off >>= 1) {
        s  += __shfl_down(s, off);
        ss += __shfl_down(ss, off);
    }
    __shared__ float red[8];
    const int w = tid >> 6, lane = tid & 63;
    if (lane == 0) { red[w] = s; red[4 + w] = ss; }
    __syncthreads();
    const float st  = red[0] + red[1] + red[2] + red[3];
    const float sst = red[4] + red[5] + red[6] + red[7];
    const float mu  = st * (1.0f / EDIM);
    const float rs  = 1.0f / sqrtf(sst * (1.0f / EDIM) - mu * mu + 1e-5f);
    float4 gg = ((const float4*)gw)[tid];
    float4 bb = ((const float4*)bw)[tid];
    float4 y;
    y.x = (v.x - mu) * rs * gg.x + bb.x;
    y.y = (v.y - mu) * rs * gg.y + bb.y;
    y.z = (v.z - mu) * rs * gg.z + bb.z;
    y.w = (v.w - mu) * rs * gg.w + bb.w;
    ((float4*)(H + (size_t)row * EDIM))[tid] = y;
    half4v h4;
    h4[0] = (_Float16)y.x; h4[1] = (_Float16)y.y;
    h4[2] = (_Float16)y.z; h4[3] = (_Float16)y.w;
    ((half4v*)(Hh + (size_t)row * EDIM))[tid] = h4;
}

// ---------------- softmax over the 64 logit columns of Theta buffer --------
// One wave per row; 4 rows per block. Logits live at Theta[row*NTC + NTRI + v].
__global__ __launch_bounds__(256) void softmax_kernel(const float* __restrict__ Theta,
                                                      float* __restrict__ pi_out,
                                                      float* __restrict__ sp) {
    const int lane = threadIdx.x & 63;
    const int row  = blockIdx.x * 4 + (threadIdx.x >> 6);
    float lg = Theta[(size_t)row * NTC + NTRI + lane];
    float m = lg;
#pragma unroll
    for (int off = 32; off; off >>= 1) m = fmaxf(m, __shfl_xor(m, off));
    float e = __expf(lg - m);
    float ssum = e;
#pragma unroll
    for (int off = 32; off; off >>= 1) ssum += __shfl_xor(ssum, off);
    float p = e / ssum;
    pi_out[(size_t)row * VDIM + lane] = p;
    sp[(size_t)row * VDIM + lane] = sqrtf(p);
}

// ---------------- Q build: one block per (b,l) row ----------------
// Q[i][j] = Theta[tri(i,j)] * sp[j]/sp[i] (i!=j), Q[i][i] = -rowsum
__global__ __launch_bounds__(256) void q_kernel(const float* __restrict__ Theta,
                                                const float* __restrict__ sp,
                                                float* __restrict__ Q) {
    const int row = blockIdx.x;
    __shared__ float Th[NTRI];
    __shared__ float spv[VDIM];
    const float* trow = Theta + (size_t)row * NTC;
    for (int t = threadIdx.x; t < NTRI; t += 256) Th[t] = trow[t];
    if (threadIdx.x < VDIM) spv[threadIdx.x] = sp[(size_t)row * VDIM + threadIdx.x];
    __syncthreads();

    const int i = threadIdx.x >> 2;   // Q row 0..63
    const int q = threadIdx.x & 3;    // col quarter
    const float rpi = 1.0f / spv[i];
    float vals[16];
    float psum = 0.f;
#pragma unroll
    for (int c = 0; c < 16; ++c) {
        const int j = q * 16 + c;
        float out = 0.f;
        if (j != i) {
            const int a = (i < j) ? i : j;
            const int b = (i < j) ? j : i;
            const int t = a * (127 - a) / 2 + (b - a - 1);
            out = Th[t] * spv[j] * rpi;
            psum += out;
        }
        vals[c] = out;
    }
    // reduce partial rowsums across the 4 threads of this row (consecutive lanes)
    psum += __shfl_xor(psum, 1);
    psum += __shfl_xor(psum, 2);

    float* qrow = Q + ((size_t)row * VDIM + i) * VDIM + q * 16;
    float4* dst = (float4*)qrow;
    dst[0] = make_float4(vals[0], vals[1], vals[2], vals[3]);
    dst[1] = make_float4(vals[4], vals[5], vals[6], vals[7]);
    dst[2] = make_float4(vals[8], vals[9], vals[10], vals[11]);
    dst[3] = make_float4(vals[12], vals[13], vals[14], vals[15]);
    if ((i >> 4) == q) {  // diagonal lies in this thread's chunk
        Q[((size_t)row * VDIM + i) * VDIM + i] = -psum;
    }
}

// ---------------- orchestration ----------------
extern "C" void kernel_launch(void* const* d_in, const int* in_sizes, int n_in,
                              void* d_out, int out_size, void* d_ws, size_t ws_size,
                              hipStream_t stream) {
    const float* hx      = (const float*)d_in[0];
    const float* W_dense = (const float*)d_in[1];
    const float* b_dense = (const float*)d_in[2];
    const float* ln_g    = (const float*)d_in[3];
    const float* ln_b    = (const float*)d_in[4];
    const float* W_theta = (const float*)d_in[5];
    const float* b_theta = (const float*)d_in[6];
    const float* W_Theta = (const float*)d_in[7];
    const float* b_Theta = (const float*)d_in[8];

    uint8_t* ws = (uint8_t*)d_ws;
    // ws layout (~94 MB peak):
    _Float16* A_h  = (_Float16*)ws;                          // 16 MB (hx fp16; later h fp16)
    _Float16* Wd_h = (_Float16*)(ws + (size_t)16 * 1048576); //  2 MB
    _Float16* Wc_h = (_Float16*)(ws + (size_t)18 * 1048576); //  4.25 MB (2176x1024: W_Theta|W_theta|0)
    float*    G    = (float*)(ws + (size_t)23 * 1048576);    // 32 MB (gelu out -> h fp32 in-place)
    float*    Theta= (float*)(ws + (size_t)23 * 1048576);    // 68 MB (8192x2176) — reuses G after LN
    float*    sp   = (float*)(ws + (size_t)92 * 1048576);    //  2 MB (sqrt(pi))

    float* Q_out  = (float*)d_out;                 // 8192*64*64
    float* pi_out = (float*)d_out + (size_t)MROWS * VDIM * VDIM;

    // 1) casts to fp16; combined theta weight = [W_Theta ; W_theta ; zeros]
    cast_f2h<<<(MROWS * EDIM / 4) / 256, 256, 0, stream>>>(hx, A_h, MROWS * EDIM, MROWS * EDIM);
    cast_f2h<<<(EDIM * EDIM / 4) / 256, 256, 0, stream>>>(W_dense, Wd_h, EDIM * EDIM, EDIM * EDIM);
    cast_f2h<<<(NTRI * EDIM / 4) / 256, 256, 0, stream>>>(W_Theta, Wc_h, NTRI * EDIM, NTRI * EDIM);
    cast_f2h<<<((NTC - NTRI) * EDIM / 4) / 256, 256, 0, stream>>>(
        W_theta, Wc_h + (size_t)NTRI * EDIM, VDIM * EDIM, (NTC - NTRI) * EDIM);

    // 2) dense GEMM + gelu -> G  (1D grid, XCD-aware mapping inside)
    gemm_bt<0><<<(EDIM / 128) * (MROWS / 128), 256, 0, stream>>>(
        A_h, Wd_h, b_dense, nullptr, G, EDIM);

    // 3) LayerNorm in-place; fp16 h into A_h (hx fp16 no longer needed)
    ln_kernel<<<MROWS, 256, 0, stream>>>(G, ln_g, ln_b, A_h);

    // 4) combined Theta+logits GEMM (softplus / raw epilogue) -> Theta buffer
    //    (overwrites G, which is dead after ln_kernel)
    gemm_bt<1><<<(NTC / 128) * (MROWS / 128), 256, 0, stream>>>(
        A_h, Wc_h, b_Theta, b_theta, Theta, NTC);

    // 5) softmax over logit columns -> pi, sqrt(pi)
    softmax_kernel<<<MROWS / 4, 256, 0, stream>>>(Theta, pi_out, sp);

    // 6) Q assembly
    q_kernel<<<MROWS, 256, 0, stream>>>(Theta, sp, Q_out);
}